// Round 7
// baseline (129.162 us; speedup 1.0000x reference)
//
#include <hip/hip_runtime.h>
#include <cstddef>
#include <cstdint>

// TemporalConvTranspose2d, R7: two-phase — transpose/convert once, LDS-free MFMA GEMM.
// x: (B, N_BI*D_IN, T) fp32, chan = s*D_IN + din
// W: (D_OUT, D_IN, K_B, K_T) fp32; b: (D_OUT,); out: (B, N_BO*D_OUT, T) fp32
// Band n = 2q+p: sources s_j = q + j + p - 1, kb = 2j+p, j in {0,1}.
// Causal time: y[t] = sum_kt W[..,kt] * x[t-2+kt].
// GEMM: out[dout,t] = sum_k A[dout,k] B[k,t], k = (j*3+kt)*32 + din (K=192).
//
// d_ws layout: [0, 24576): wt (A fragments, wprep — verified R5 layout)
//              [65536, 65536 + 8*34*1024*32*2): xw[b][sl][tp][din] bf16
//                sl = s+1 in [0,34) (halo bands 0 and 33 are zeros),
//                tp = t+4 in [0,1024) (rows 0-3 and 1004+ are zeros).
// B-frag load: lane l -> 16B at row tp = tcol + kt + 2, chunk (l>>4): a wave
// covers 16 rows x 64B = 1KB dense. No LDS anywhere in the GEMM.

typedef __bf16 bf16x8 __attribute__((ext_vector_type(8)));
typedef __bf16 bf16x4 __attribute__((ext_vector_type(4)));
typedef float  f32x4  __attribute__((ext_vector_type(4)));

#define D_IN_ 32
#define D_OUT_ 32
#define N_BI_ 32
#define N_BO_ 64
#define K_B_ 4
#define K_T_ 3
#define T_ 1000
#define B_ 8

#define TPB_ 1024                 // padded t rows per band slot
#define ROWB_ 64                  // bytes per row (32 din * 2B)
#define NSL_ 34                   // band slots (with halo)
#define WT_ELEMS (2 * 6 * 2 * 64 * 8)            // 12288 bf16 = 24576 B
#define XW_OFF_ 65536
#define XW_BYTES_ ((size_t)B_ * NSL_ * TPB_ * ROWB_)   // 17,825,792
#define WS_NEED_ (XW_OFF_ + XW_BYTES_)

// ---- A fragments (verified R5 layout) ----
__global__ __launch_bounds__(256)
void wprep(const float* __restrict__ W, __bf16* __restrict__ wt) {
    int idx = blockIdx.x * 256 + threadIdx.x;
    if (idx >= WT_ELEMS) return;
    int r = idx & 7, l = (idx >> 3) & 63, mt = (idx >> 9) & 1, rest = idx >> 10;
    int ks = rest % 6, p = rest / 6;
    int dout = mt * 16 + (l & 15), din = (l >> 4) * 8 + r;
    int j = ks / 3, kt = ks % 3, kb = 2 * j + p;
    wt[idx] = (__bf16)W[((dout * D_IN_ + din) * K_B_ + kb) * K_T_ + kt];
}

// ---- transpose+convert x into xw (also zero-fills halos/pads) ----
// grid (TPB_/64, NSL_, B_), block 256. thread: row tp = tp0 + (i>>2),
// chunk = i&3 (8 din). 8 strided scalar loads -> bf16x8 -> one dwordx4 store.
__global__ __launch_bounds__(256)
void xprep(const float* __restrict__ x, __bf16* __restrict__ xw) {
    const int i   = threadIdx.x;
    const int tp  = blockIdx.x * 64 + (i >> 2);
    const int ch  = i & 3;
    const int sl  = blockIdx.y;
    const int bb  = blockIdx.z;
    const int s   = sl - 1;
    const int t   = tp - 4;
    const bool ok = (s >= 0) && (s < N_BI_) && (t >= 0) && (t < T_);

    bf16x8 v;
    if (ok) {
        const float* xp = x + ((size_t)(bb * N_BI_ + s) * D_IN_ + ch * 8) * T_ + t;
#pragma unroll
        for (int r = 0; r < 8; ++r) v[r] = (__bf16)xp[(size_t)r * T_];
    } else {
#pragma unroll
        for (int r = 0; r < 8; ++r) v[r] = (__bf16)0.f;
    }
    __bf16* dst = xw + ((size_t)(bb * NSL_ + sl) * TPB_ + tp) * D_IN_ + ch * 8;
    *(bf16x8*)dst = v;
}

// ---- LDS-free MFMA GEMM ----
// grid (4, N_BO_, B_), block 512 = 8 waves: wave w -> mt = w>>2, t-quarter w&3.
// TT = 250 output t per block (t0 = bx*250); wave covers 64 t (tail masked).
__global__ __launch_bounds__(512)
void tct_gemm(const __bf16* __restrict__ xw, const __bf16* __restrict__ wt,
              const float* __restrict__ bias, float* __restrict__ out)
{
    const int tid = threadIdx.x;
    const int l   = tid & 63;
    const int w   = tid >> 6;
    const int mtw = w >> 2;            // 0/1: dout half
    const int wq  = w & 3;             // t-quarter (64 t each)
    const int tl  = l & 15;
    const int cch = l >> 4;
    const int n   = blockIdx.y;
    const int bb  = blockIdx.z;
    const int p   = n & 1, q = n >> 1;
    const int t0  = blockIdx.x * 250;

    // A fragments for this wave's dout half (L2-hot, block-uniform).
    bf16x8 afrag[6];
    {
        const bf16x8* wp = (const bf16x8*)wt;
        const int base = p * 768 + mtw * 64;
#pragma unroll
        for (int ks = 0; ks < 6; ++ks)
            afrag[ks] = wp[base + ks * 128 + l];
    }

    // Source band rows (bf16, [tp][din]); sl = q + j + p in [0,33] always valid.
    const char* xb0 = (const char*)(xw + ((size_t)(bb * NSL_ + (q + p)) * TPB_) * D_IN_);
    const char* xb1 = xb0 + (size_t)TPB_ * ROWB_;   // sl+1

    f32x4 acc[4];
#pragma unroll
    for (int nt = 0; nt < 4; ++nt)
#pragma unroll
        for (int r = 0; r < 4; ++r) acc[nt][r] = 0.f;

#pragma unroll
    for (int nt = 0; nt < 4; ++nt) {
        const int tcol = t0 + wq * 64 + nt * 16 + tl;
        bf16x8 bfrag[6];
#pragma unroll
        for (int kt = 0; kt < 3; ++kt) {
            const int tp = tcol + kt + 2;          // = (t + kt - 2) + 4, <= 1009
            bfrag[kt]     = *(const bf16x8*)(xb0 + (size_t)tp * ROWB_ + cch * 16);
            bfrag[3 + kt] = *(const bf16x8*)(xb1 + (size_t)tp * ROWB_ + cch * 16);
        }
#pragma unroll
        for (int ks = 0; ks < 6; ++ks)
            acc[nt] = __builtin_amdgcn_mfma_f32_16x16x32_bf16(afrag[ks], bfrag[ks], acc[nt], 0, 0, 0);
    }

    // Epilogue: C/D layout col = l&15 (t), row = (l>>4)*4 + r (dout in half).
    const int rbase = cch * 4;
    float bv[4];
#pragma unroll
    for (int r = 0; r < 4; ++r) bv[r] = bias[mtw * 16 + rbase + r];

#pragma unroll
    for (int nt = 0; nt < 4; ++nt) {
        const int lcol = wq * 64 + nt * 16 + tl;
        const int tcol = t0 + lcol;
        if (lcol < 250) {                          // t0+250 <= 1000 always
            float* op = out + ((size_t)(bb * N_BO_ + n) * D_OUT_ + mtw * 16 + rbase) * T_ + tcol;
#pragma unroll
            for (int r = 0; r < 4; ++r)
                op[(size_t)r * T_] = acc[nt][r] + bv[r];
        }
    }
}

// ---- mid-tier fallback: verified R6 LDS kernel (needs only 24KB ws) ----
#define TT6_ 252
#define XROWS_ 260
__device__ __forceinline__ int swz(int t) { return (t & 3) ^ ((t >> 2) & 3); }

__global__ __launch_bounds__(512, 4)
void tct_mfma(const float* __restrict__ x, const __bf16* __restrict__ wt,
              const float* __restrict__ bias, float* __restrict__ out)
{
    __shared__ unsigned char xl[2 * XROWS_ * ROWB_];
    const int tid = threadIdx.x;
    const int l   = tid & 63;
    const int w   = tid >> 6;
    const int n   = blockIdx.y;
    const int bb  = blockIdx.z;
    const int p   = n & 1, q = n >> 1;
    const int t0  = blockIdx.x * TT6_;
    const int tstart = t0 - 4;

    bf16x8 afrag[6][2];
    {
        const bf16x8* wp = (const bf16x8*)wt;
        const int base = p * 12 * 64;
#pragma unroll
        for (int ks = 0; ks < 6; ++ks)
#pragma unroll
            for (int mt = 0; mt < 2; ++mt)
                afrag[ks][mt] = wp[base + (ks * 2 + mt) * 64 + l];
    }
    {
        const int g  = tid >> 4;
        const int u  = tid & 15;
        const int si = u >> 3;
        const int dg = u & 7;
        const int s  = q + si + p - 1;
        const bool bandok = (s >= 0) && (s < N_BI_);
        const float* xb = x + ((size_t)(bb * N_BI_ + (bandok ? s : 0)) * D_IN_ + dg * 4) * T_;
        unsigned char* lbase = xl + si * (XROWS_ * ROWB_);
        const int c = dg >> 1, h = dg & 1;
        f32x4 vv[2][4];
        bool ok[2];
#pragma unroll
        for (int it = 0; it < 2; ++it) {
            const int tg = tstart + (g + it * 32) * 4;
            ok[it] = bandok && (tg >= 0) && (tg < T_);
#pragma unroll
            for (int i = 0; i < 4; ++i)
                vv[it][i] = ok[it] ? *(const f32x4*)(xb + (size_t)i * T_ + tg)
                                   : (f32x4){0.f, 0.f, 0.f, 0.f};
        }
#pragma unroll
        for (int it = 0; it < 2; ++it) {
            const int tq = g + it * 32;
#pragma unroll
            for (int jj = 0; jj < 4; ++jj) {
                const int k = (jj + g) & 3;
                const int t = tq * 4 + k;
                bf16x4 row;
                row[0] = (__bf16)vv[it][0][k]; row[1] = (__bf16)vv[it][1][k];
                row[2] = (__bf16)vv[it][2][k]; row[3] = (__bf16)vv[it][3][k];
                *(bf16x4*)(lbase + t * ROWB_ + ((c ^ swz(t)) << 4) + (h << 3)) = row;
            }
        }
    }
    __syncthreads();

    f32x4 acc[2][2];
#pragma unroll
    for (int mt = 0; mt < 2; ++mt)
#pragma unroll
        for (int nt = 0; nt < 2; ++nt)
#pragma unroll
            for (int r = 0; r < 4; ++r) acc[mt][nt][r] = 0.f;

    const int tl  = l & 15;
    const int cch = l >> 4;
#pragma unroll
    for (int nt = 0; nt < 2; ++nt) {
#pragma unroll
        for (int ks = 0; ks < 6; ++ks) {
            const int j  = ks / 3, kt = ks % 3;
            const int lt = w * 32 + nt * 16 + tl + kt + 2;
            const bf16x8 bfrag = *(const bf16x8*)(xl + j * (XROWS_ * ROWB_) + lt * ROWB_
                                                  + ((cch ^ swz(lt)) << 4));
            acc[0][nt] = __builtin_amdgcn_mfma_f32_16x16x32_bf16(afrag[ks][0], bfrag, acc[0][nt], 0, 0, 0);
            acc[1][nt] = __builtin_amdgcn_mfma_f32_16x16x32_bf16(afrag[ks][1], bfrag, acc[1][nt], 0, 0, 0);
        }
    }
    const int rbase = (l >> 4) * 4;
    float bv[2][4];
#pragma unroll
    for (int mt = 0; mt < 2; ++mt)
#pragma unroll
        for (int r = 0; r < 4; ++r) bv[mt][r] = bias[mt * 16 + rbase + r];
#pragma unroll
    for (int mt = 0; mt < 2; ++mt)
#pragma unroll
        for (int nt = 0; nt < 2; ++nt) {
            const int lcol = w * 32 + nt * 16 + tl;
            const int tcol = t0 + lcol;
            if (lcol < TT6_ && tcol < T_) {
                float* op = out + ((size_t)(bb * N_BO_ + n) * D_OUT_ + mt * 16 + rbase) * T_ + tcol;
#pragma unroll
                for (int r = 0; r < 4; ++r)
                    op[(size_t)r * T_] = acc[mt][nt][r] + bv[r == r ? mt : mt][r];
            }
        }
}

// ---- fp32 fallback (no ws) ----
__global__ __launch_bounds__(256)
void tct_fallback(const float* __restrict__ x, const float* __restrict__ W,
                  const float* __restrict__ bias, float* __restrict__ out)
{
    const int lane = threadIdx.x & 63;
    const int wav  = __builtin_amdgcn_readfirstlane(threadIdx.x >> 6);
    const int dog  = wav * 8;
    const int n    = blockIdx.y;
    const int bb   = blockIdx.z;
    const int p    = n & 1;
    int t0 = blockIdx.x * 256 + lane * 4;
    const bool act = (t0 < T_);
    if (!act) t0 = T_ - 4;
    float acc[8][4];
#pragma unroll
    for (int i = 0; i < 8; ++i)
#pragma unroll
        for (int u = 0; u < 4; ++u) acc[i][u] = 0.f;
#pragma unroll
    for (int j = 0; j < 2; ++j) {
        const int s = (n + 2 * j + p - 2) >> 1;
        if (s < 0 || s >= N_BI_) continue;
        const int kb = 2 * j + p;
        const float* xband = x + (size_t)(bb * N_BI_ + s) * D_IN_ * T_;
        for (int d_in = 0; d_in < D_IN_; ++d_in) {
            const float* xr = xband + d_in * T_;
            const float4 xc = *(const float4*)(xr + t0);
            float4 xp = make_float4(0.f, 0.f, 0.f, 0.f);
            if (t0 > 0) xp = *(const float4*)(xr + t0 - 4);
            const float xv[6] = {xp.z, xp.w, xc.x, xc.y, xc.z, xc.w};
#pragma unroll
            for (int kt = 0; kt < K_T_; ++kt) {
                float wv[8];
#pragma unroll
                for (int i = 0; i < 8; ++i) {
                    const int widx = __builtin_amdgcn_readfirstlane(
                        (((dog + i) * D_IN_ + d_in) * K_B_ + kb) * K_T_ + kt);
                    wv[i] = W[widx];
                }
#pragma unroll
                for (int i = 0; i < 8; ++i)
#pragma unroll
                    for (int u = 0; u < 4; ++u)
                        acc[i][u] = fmaf(wv[i], xv[u + kt], acc[i][u]);
            }
        }
    }
    if (act) {
        float bvv[8];
#pragma unroll
        for (int i = 0; i < 8; ++i) bvv[i] = bias[dog + i];
        float* op = out + ((size_t)(bb * N_BO_ + n) * D_OUT_ + dog) * T_ + t0;
#pragma unroll
        for (int i = 0; i < 8; ++i) {
            float4 v;
            v.x = acc[i][0] + bvv[i]; v.y = acc[i][1] + bvv[i];
            v.z = acc[i][2] + bvv[i]; v.w = acc[i][3] + bvv[i];
            *(float4*)(op + (size_t)i * T_) = v;
        }
    }
}

extern "C" void kernel_launch(void* const* d_in, const int* in_sizes, int n_in,
                              void* d_out, int out_size, void* d_ws, size_t ws_size,
                              hipStream_t stream) {
    const float* x    = (const float*)d_in[0];
    const float* W    = (const float*)d_in[1];
    const float* bias = (const float*)d_in[2];
    float* out = (float*)d_out;

    if (ws_size >= WS_NEED_) {
        __bf16* wt = (__bf16*)d_ws;
        __bf16* xw = (__bf16*)((char*)d_ws + XW_OFF_);
        wprep<<<(WT_ELEMS + 255) / 256, 256, 0, stream>>>(W, wt);
        xprep<<<dim3(TPB_ / 64, NSL_, B_), dim3(256), 0, stream>>>(x, xw);
        tct_gemm<<<dim3(4, N_BO_, B_), dim3(512), 0, stream>>>(xw, wt, bias, out);
    } else if (ws_size >= (size_t)WT_ELEMS * sizeof(__bf16)) {
        __bf16* wt = (__bf16*)d_ws;
        wprep<<<(WT_ELEMS + 255) / 256, 256, 0, stream>>>(W, wt);
        tct_mfma<<<dim3((T_ + TT6_ - 1) / TT6_, N_BO_, B_), dim3(512), 0, stream>>>(x, wt, bias, out);
    } else {
        tct_fallback<<<dim3((T_ + 255) / 256, N_BO_, B_), dim3(256), 0, stream>>>(x, W, bias, out);
    }
}

// Round 8
// 110.872 us; speedup vs baseline: 1.1650x; 1.1650x over previous
//
#include <hip/hip_runtime.h>
#include <cstddef>
#include <cstdint>

// TemporalConvTranspose2d, R8: band-paired fused MFMA kernel.
// x: (B, N_BI*D_IN, T) fp32, chan = s*D_IN + din
// W: (D_OUT, D_IN, K_B, K_T) fp32; b: (D_OUT,); out: (B, N_BO*D_OUT, T) fp32
// Band n = 2q+p: sources s_j = q+j+p-1, kb = 2j+p, j in {0,1}.
// KEY: outputs n=2k+1 (p=1) and n=2k+2 (p=0) both source bands {k, k+1} with
// identical B-fragments; only the A weight planes differ (kb = 2j+1 vs 2j).
// One block stages bands {k,k+1} once -> computes BOTH output bands:
// staging and ds_reads per output halved vs R5.
// GEMM per n: out[dout,t] = sum_k A[dout,k] B[k,t], k=(j*3+kt)*32+din, K=192.
// MFMA 16x16x32 bf16, fp32 accum. Verified R5 layouts throughout.

typedef __bf16 bf16x8 __attribute__((ext_vector_type(8)));
typedef __bf16 bf16x4 __attribute__((ext_vector_type(4)));
typedef float  f32x4  __attribute__((ext_vector_type(4)));

#define D_IN_ 32
#define D_OUT_ 32
#define N_BI_ 32
#define N_BO_ 64
#define K_B_ 4
#define K_T_ 3
#define T_ 1000
#define B_ 8

#define TT_ 252                  // output t per block
#define XROWS_ 260               // LDS rows per band (256 staged + 4 pad)
#define ROWB_ 64                 // bytes per LDS row (32 din * 2B)
#define WT_ELEMS (2 * 6 * 2 * 64 * 8)   // 12288 bf16 = 24576 B

__device__ __forceinline__ int swz(int t) { return (t & 3) ^ ((t >> 2) & 3); }

// A fragments (verified R5 layout): wt[((p*6+ks)*2+mt)*64 + l], 8 bf16 each:
// dout = mt*16 + (l&15), din = (l>>4)*8 + r, (j,kt) = (ks/3, ks%3), kb = 2j+p.
__global__ __launch_bounds__(256)
void wprep(const float* __restrict__ W, __bf16* __restrict__ wt) {
    int idx = blockIdx.x * 256 + threadIdx.x;
    if (idx >= WT_ELEMS) return;
    int r = idx & 7, l = (idx >> 3) & 63, mt = (idx >> 9) & 1, rest = idx >> 10;
    int ks = rest % 6, p = rest / 6;
    int dout = mt * 16 + (l & 15), din = (l >> 4) * 8 + r;
    int j = ks / 3, kt = ks % 3, kb = 2 * j + p;
    wt[idx] = (__bf16)W[((dout * D_IN_ + din) * K_B_ + kb) * K_T_ + kt];
}

// Fused band-pair kernel. grid (4, 33, 8), block 512 = 8 waves.
// blockIdx.y = k+1, k in [-1, 31]; stages bands {k, k+1} (invalid -> zeros);
// outputs n = 2k+2-p for p in {0,1}, guarded to [0,64).
// Wave w: mt = w>>2 (dout half), wq = w&3 (64-t chunk).
__global__ __launch_bounds__(512)
void tct_pair(const float* __restrict__ x, const __bf16* __restrict__ wt,
              const float* __restrict__ bias, float* __restrict__ out)
{
    __shared__ unsigned char xl[2 * XROWS_ * ROWB_];   // 33280 B

    const int tid = threadIdx.x;
    const int l   = tid & 63;
    const int w   = tid >> 6;
    const int mt  = w >> 2;
    const int wq  = w & 3;
    const int tl  = l & 15;
    const int cch = l >> 4;
    const int k   = (int)blockIdx.y - 1;
    const int bb  = blockIdx.z;
    const int t0  = blockIdx.x * TT_;

    // ---- A fragments: both parities for this wave's dout half ----
    bf16x8 afrag[2][6];
    {
        const bf16x8* wp = (const bf16x8*)wt;
#pragma unroll
        for (int p = 0; p < 2; ++p)
#pragma unroll
            for (int ks = 0; ks < 6; ++ks)
                afrag[p][ks] = wp[p * 768 + ks * 128 + mt * 64 + l];
    }

    // ---- stage bands {k, k+1} -> LDS bf16 [si][t][din], R5 swizzle ----
    // 2 bands x 64 t-quads over 32 quad-groups: 2 quad-slots per thread,
    // all 8 global float4 loads hoisted before conversion/writes.
    {
        const int g  = tid >> 4;       // quad-group 0..31
        const int u  = tid & 15;
        const int si = u >> 3;         // band slot 0/1
        const int dg = u & 7;          // din group of 4
        const int s  = k + si;
        const bool bandok = (s >= 0) && (s < N_BI_);
        const float* xb = x + ((size_t)(bb * N_BI_ + (bandok ? s : 0)) * D_IN_ + dg * 4) * T_;
        unsigned char* lbase = xl + si * (XROWS_ * ROWB_);
        const int c = dg >> 1, h = dg & 1;

        f32x4 vv[2][4];
        bool ok[2];
#pragma unroll
        for (int it = 0; it < 2; ++it) {
            const int tg = t0 - 4 + (g + it * 32) * 4;   // quad-aligned
            ok[it] = bandok && (tg >= 0) && (tg < T_);    // full quad valid
#pragma unroll
            for (int i = 0; i < 4; ++i)
                vv[it][i] = ok[it] ? *(const f32x4*)(xb + (size_t)i * T_ + tg)
                                   : (f32x4){0.f, 0.f, 0.f, 0.f};
        }
#pragma unroll
        for (int it = 0; it < 2; ++it) {
            const int tq = g + it * 32;
#pragma unroll
            for (int kk = 0; kk < 4; ++kk) {
                const int t = tq * 4 + kk;
                bf16x4 row;
                row[0] = (__bf16)vv[it][0][kk];
                row[1] = (__bf16)vv[it][1][kk];
                row[2] = (__bf16)vv[it][2][kk];
                row[3] = (__bf16)vv[it][3][kk];
                *(bf16x4*)(lbase + t * ROWB_ + ((c ^ swz(t)) << 4) + (h << 3)) = row;
            }
        }
    }
    __syncthreads();

    // ---- main loop: 4 nt x 6 (j,kt); each ds_read feeds 2 MFMAs (p=0,1) ----
    f32x4 acc[2][4];
#pragma unroll
    for (int p = 0; p < 2; ++p)
#pragma unroll
        for (int nt = 0; nt < 4; ++nt)
#pragma unroll
            for (int r = 0; r < 4; ++r) acc[p][nt][r] = 0.f;

#pragma unroll
    for (int nt = 0; nt < 4; ++nt) {
#pragma unroll
        for (int j = 0; j < 2; ++j) {
            const unsigned char* xbnd = xl + j * (XROWS_ * ROWB_);
#pragma unroll
            for (int kt = 0; kt < 3; ++kt) {
                const int lt = wq * 64 + nt * 16 + tl + kt + 2;   // <= 259
                const bf16x8 bfrag = *(const bf16x8*)(xbnd + lt * ROWB_
                                                      + ((cch ^ swz(lt)) << 4));
                const int ks = j * 3 + kt;
                acc[0][nt] = __builtin_amdgcn_mfma_f32_16x16x32_bf16(afrag[0][ks], bfrag, acc[0][nt], 0, 0, 0);
                acc[1][nt] = __builtin_amdgcn_mfma_f32_16x16x32_bf16(afrag[1][ks], bfrag, acc[1][nt], 0, 0, 0);
            }
        }
    }

    // ---- epilogue: C/D col = l&15 (t), row = cch*4 + r (dout in mt half) ----
    const int rbase = cch * 4;
    float bv[4];
#pragma unroll
    for (int r = 0; r < 4; ++r) bv[r] = bias[mt * 16 + rbase + r];

#pragma unroll
    for (int p = 0; p < 2; ++p) {
        const int n = 2 * k + 2 - p;        // p=1 -> 2k+1, p=0 -> 2k+2
        if (n < 0 || n >= N_BO_) continue;
        float* opb = out + ((size_t)(bb * N_BO_ + n) * D_OUT_ + mt * 16 + rbase) * T_;
#pragma unroll
        for (int nt = 0; nt < 4; ++nt) {
            const int lcol = wq * 64 + nt * 16 + tl;
            const int tcol = t0 + lcol;
            if (lcol < TT_ && tcol < T_) {
#pragma unroll
                for (int r = 0; r < 4; ++r)
                    opb[(size_t)r * T_ + tcol] = acc[p][nt][r] + bv[r];
            }
        }
    }
}

// ---- fp32 fallback (no ws) ----
__global__ __launch_bounds__(256)
void tct_fallback(const float* __restrict__ x, const float* __restrict__ W,
                  const float* __restrict__ bias, float* __restrict__ out)
{
    const int lane = threadIdx.x & 63;
    const int wav  = __builtin_amdgcn_readfirstlane(threadIdx.x >> 6);
    const int dog  = wav * 8;
    const int n    = blockIdx.y;
    const int bb   = blockIdx.z;
    const int p    = n & 1;
    int t0 = blockIdx.x * 256 + lane * 4;
    const bool act = (t0 < T_);
    if (!act) t0 = T_ - 4;
    float acc[8][4];
#pragma unroll
    for (int i = 0; i < 8; ++i)
#pragma unroll
        for (int u = 0; u < 4; ++u) acc[i][u] = 0.f;
#pragma unroll
    for (int j = 0; j < 2; ++j) {
        const int s = (n + 2 * j + p - 2) >> 1;
        if (s < 0 || s >= N_BI_) continue;
        const int kb = 2 * j + p;
        const float* xband = x + (size_t)(bb * N_BI_ + s) * D_IN_ * T_;
        for (int d_in = 0; d_in < D_IN_; ++d_in) {
            const float* xr = xband + d_in * T_;
            const float4 xc = *(const float4*)(xr + t0);
            float4 xp = make_float4(0.f, 0.f, 0.f, 0.f);
            if (t0 > 0) xp = *(const float4*)(xr + t0 - 4);
            const float xv[6] = {xp.z, xp.w, xc.x, xc.y, xc.z, xc.w};
#pragma unroll
            for (int kt = 0; kt < K_T_; ++kt) {
                float wv[8];
#pragma unroll
                for (int i = 0; i < 8; ++i) {
                    const int widx = __builtin_amdgcn_readfirstlane(
                        (((dog + i) * D_IN_ + d_in) * K_B_ + kb) * K_T_ + kt);
                    wv[i] = W[widx];
                }
#pragma unroll
                for (int i = 0; i < 8; ++i)
#pragma unroll
                    for (int u = 0; u < 4; ++u)
                        acc[i][u] = fmaf(wv[i], xv[u + kt], acc[i][u]);
            }
        }
    }
    if (act) {
        float bvv[8];
#pragma unroll
        for (int i = 0; i < 8; ++i) bvv[i] = bias[dog + i];
        float* op = out + ((size_t)(bb * N_BO_ + n) * D_OUT_ + dog) * T_ + t0;
#pragma unroll
        for (int i = 0; i < 8; ++i) {
            float4 v;
            v.x = acc[i][0] + bvv[i]; v.y = acc[i][1] + bvv[i];
            v.z = acc[i][2] + bvv[i]; v.w = acc[i][3] + bvv[i];
            *(float4*)(op + (size_t)i * T_) = v;
        }
    }
}

extern "C" void kernel_launch(void* const* d_in, const int* in_sizes, int n_in,
                              void* d_out, int out_size, void* d_ws, size_t ws_size,
                              hipStream_t stream) {
    const float* x    = (const float*)d_in[0];
    const float* W    = (const float*)d_in[1];
    const float* bias = (const float*)d_in[2];
    float* out = (float*)d_out;

    if (ws_size >= (size_t)WT_ELEMS * sizeof(__bf16)) {
        __bf16* wt = (__bf16*)d_ws;
        wprep<<<(WT_ELEMS + 255) / 256, 256, 0, stream>>>(W, wt);
        dim3 grid((T_ + TT_ - 1) / TT_, N_BO_ / 2 + 1, B_);   // 4 x 33 x 8
        tct_pair<<<grid, dim3(512), 0, stream>>>(x, wt, bias, out);
    } else {
        tct_fallback<<<dim3((T_ + 255) / 256, N_BO_, B_), dim3(256), 0, stream>>>(x, W, bias, out);
    }
}

// Round 9
// 106.052 us; speedup vs baseline: 1.2179x; 1.0455x over previous
//
#include <hip/hip_runtime.h>
#include <cstddef>
#include <cstdint>

// TemporalConvTranspose2d, R9: band-paired MFMA kernel, big t-tile + XCD grouping.
// x: (B, N_BI*D_IN, T) fp32, chan = s*D_IN + din
// W: (D_OUT, D_IN, K_B, K_T) fp32; b: (D_OUT,); out: (B, N_BO*D_OUT, T) fp32
// Band n = 2q+p: sources s_j = q+j+p-1, kb = 2j+p, j in {0,1}.
// Outputs n=2k+1 (p=1) and n=2k+2 (p=0) share source bands {k,k+1} and
// B-fragments; only A weight planes differ. One block = one (bb, k, t-half):
// t-tile 500 (2KB contiguous read chunks per x-row), LDS 2 bands x 512 rows.
// 1D grid 528, bb = wgid&7 -> all blocks of a batch on one XCD (L2 band reuse).
// GEMM per n: out[dout,t] = sum_k A[dout,k] B[k,t], k=(j*3+kt)*32+din, K=192.
// MFMA 16x16x32 bf16, fp32 accum. Verified R5/R8 layouts throughout.

typedef __bf16 bf16x8 __attribute__((ext_vector_type(8)));
typedef __bf16 bf16x4 __attribute__((ext_vector_type(4)));
typedef float  f32x4  __attribute__((ext_vector_type(4)));

#define D_IN_ 32
#define D_OUT_ 32
#define N_BI_ 32
#define N_BO_ 64
#define K_B_ 4
#define K_T_ 3
#define T_ 1000
#define B_ 8

#define TT_ 500                  // output t per block (2 tiles cover T)
#define XR_ 512                  // staged rows per band: t in [t0-4, t0+508)
#define ROWB_ 64                 // bytes per LDS row (32 din * 2B)
#define WT_ELEMS (2 * 6 * 2 * 64 * 8)   // 12288 bf16 = 24576 B

__device__ __forceinline__ int swz(int t) { return (t & 3) ^ ((t >> 2) & 3); }

// A fragments (verified R5 layout): wt[((p*6+ks)*2+mt)*64 + l], 8 bf16 each:
// dout = mt*16 + (l&15), din = (l>>4)*8 + r, (j,kt) = (ks/3, ks%3), kb = 2j+p.
__global__ __launch_bounds__(256)
void wprep(const float* __restrict__ W, __bf16* __restrict__ wt) {
    int idx = blockIdx.x * 256 + threadIdx.x;
    if (idx >= WT_ELEMS) return;
    int r = idx & 7, l = (idx >> 3) & 63, mt = (idx >> 9) & 1, rest = idx >> 10;
    int ks = rest % 6, p = rest / 6;
    int dout = mt * 16 + (l & 15), din = (l >> 4) * 8 + r;
    int j = ks / 3, kt = ks % 3, kb = 2 * j + p;
    wt[idx] = (__bf16)W[((dout * D_IN_ + din) * K_B_ + kb) * K_T_ + kt];
}

// 1D grid 528 = 8 bb x 33 kk x 2 th. bb = wgid&7 (XCD grouping heuristic).
// Block: stages bands {k, k+1} for t in [t0-4, t0+508); outputs n = 2k+2-p.
// 8 waves: mt = w>>2 (dout half), wq = w&3 (128-t chunk).
__global__ __launch_bounds__(512, 2)
void tct_pair(const float* __restrict__ x, const __bf16* __restrict__ wt,
              const float* __restrict__ bias, float* __restrict__ out)
{
    __shared__ unsigned char xl[2 * XR_ * ROWB_];   // 65536 B

    const int wg  = blockIdx.x;
    const int bb  = wg & 7;
    const int rr  = wg >> 3;          // 0..65
    const int kk  = rr >> 1;          // 0..32
    const int th  = rr & 1;
    const int k   = kk - 1;
    const int t0  = th * TT_;

    const int tid = threadIdx.x;
    const int l   = tid & 63;
    const int w   = tid >> 6;
    const int mt  = w >> 2;
    const int wq  = w & 3;
    const int tl  = l & 15;
    const int cch = l >> 4;

    // ---- stage bands {k, k+1} -> LDS bf16 [si][row][din], R5 swizzle ----
    // per (si, dg): 128 t-quads over 32 quad-groups: 4 quad-slots per thread.
    {
        const int g  = tid >> 4;       // quad-group 0..31
        const int u  = tid & 15;
        const int si = u >> 3;         // band slot 0/1
        const int dg = u & 7;          // din group of 4
        const int s  = k + si;
        const bool bandok = (s >= 0) && (s < N_BI_);
        const float* xb = x + ((size_t)(bb * N_BI_ + (bandok ? s : 0)) * D_IN_ + dg * 4) * T_;
        unsigned char* lbase = xl + si * (XR_ * ROWB_);
        const int c = dg >> 1, h = dg & 1;

        f32x4 vv[4][4];
#pragma unroll
        for (int it = 0; it < 4; ++it) {
            const int tg = t0 - 4 + (g + it * 32) * 4;   // quad-aligned
            const bool ok = bandok && (tg >= 0) && (tg < T_);
#pragma unroll
            for (int i = 0; i < 4; ++i)
                vv[it][i] = ok ? *(const f32x4*)(xb + (size_t)i * T_ + tg)
                               : (f32x4){0.f, 0.f, 0.f, 0.f};
        }
#pragma unroll
        for (int it = 0; it < 4; ++it) {
            const int tq = g + it * 32;
#pragma unroll
            for (int e = 0; e < 4; ++e) {
                const int t = tq * 4 + e;                // local row 0..511
                bf16x4 row;
                row[0] = (__bf16)vv[it][0][e];
                row[1] = (__bf16)vv[it][1][e];
                row[2] = (__bf16)vv[it][2][e];
                row[3] = (__bf16)vv[it][3][e];
                *(bf16x4*)(lbase + t * ROWB_ + ((c ^ swz(t)) << 4) + (h << 3)) = row;
            }
        }
    }

    // ---- A fragments: both parities for this wave's dout half ----
    bf16x8 afrag[2][6];
    {
        const bf16x8* wp = (const bf16x8*)wt;
#pragma unroll
        for (int p = 0; p < 2; ++p)
#pragma unroll
            for (int ks = 0; ks < 6; ++ks)
                afrag[p][ks] = wp[p * 768 + ks * 128 + mt * 64 + l];
    }

    const int rbase = cch * 4;
    float bv[4];
#pragma unroll
    for (int r = 0; r < 4; ++r) bv[r] = bias[mt * 16 + rbase + r];

    __syncthreads();

    // ---- main loop: 2 chunks x 4 nt x 6 (j,kt); 1 ds_read feeds 2 MFMAs ----
#pragma unroll
    for (int ntc = 0; ntc < 2; ++ntc) {
        f32x4 acc[2][4];
#pragma unroll
        for (int p = 0; p < 2; ++p)
#pragma unroll
            for (int n4 = 0; n4 < 4; ++n4)
#pragma unroll
                for (int r = 0; r < 4; ++r) acc[p][n4][r] = 0.f;

#pragma unroll
        for (int n4 = 0; n4 < 4; ++n4) {
            const int nt = ntc * 4 + n4;
#pragma unroll
            for (int j = 0; j < 2; ++j) {
                const unsigned char* xbnd = xl + j * (XR_ * ROWB_);
#pragma unroll
                for (int kt = 0; kt < 3; ++kt) {
                    // local row = lcol + kt + 2; wrap (&511) only hits lanes
                    // whose outputs are masked (lcol >= 500).
                    const int lt = (wq * 128 + nt * 16 + tl + kt + 2) & (XR_ - 1);
                    const bf16x8 bfrag = *(const bf16x8*)(xbnd + lt * ROWB_
                                                          + ((cch ^ swz(lt)) << 4));
                    const int ks = j * 3 + kt;
                    acc[0][n4] = __builtin_amdgcn_mfma_f32_16x16x32_bf16(afrag[0][ks], bfrag, acc[0][n4], 0, 0, 0);
                    acc[1][n4] = __builtin_amdgcn_mfma_f32_16x16x32_bf16(afrag[1][ks], bfrag, acc[1][n4], 0, 0, 0);
                }
            }
        }

        // ---- epilogue: C/D col = l&15 (t), row = cch*4 + r (dout) ----
#pragma unroll
        for (int p = 0; p < 2; ++p) {
            const int n = 2 * k + 2 - p;       // p=1 -> 2k+1, p=0 -> 2k+2
            if (n < 0 || n >= N_BO_) continue;
            float* opb = out + ((size_t)(bb * N_BO_ + n) * D_OUT_ + mt * 16 + rbase) * T_;
#pragma unroll
            for (int n4 = 0; n4 < 4; ++n4) {
                const int lcol = wq * 128 + (ntc * 4 + n4) * 16 + tl;
                if (lcol < TT_) {              // t0 + lcol <= 999 guaranteed
                    const int tcol = t0 + lcol;
#pragma unroll
                    for (int r = 0; r < 4; ++r)
                        opb[(size_t)r * T_ + tcol] = acc[p][n4][r] + bv[r];
                }
            }
        }
    }
}

// ---- fp32 fallback (no ws) ----
__global__ __launch_bounds__(256)
void tct_fallback(const float* __restrict__ x, const float* __restrict__ W,
                  const float* __restrict__ bias, float* __restrict__ out)
{
    const int lane = threadIdx.x & 63;
    const int wav  = __builtin_amdgcn_readfirstlane(threadIdx.x >> 6);
    const int dog  = wav * 8;
    const int n    = blockIdx.y;
    const int bb   = blockIdx.z;
    const int p    = n & 1;
    int t0 = blockIdx.x * 256 + lane * 4;
    const bool act = (t0 < T_);
    if (!act) t0 = T_ - 4;
    float acc[8][4];
#pragma unroll
    for (int i = 0; i < 8; ++i)
#pragma unroll
        for (int u = 0; u < 4; ++u) acc[i][u] = 0.f;
#pragma unroll
    for (int j = 0; j < 2; ++j) {
        const int s = (n + 2 * j + p - 2) >> 1;
        if (s < 0 || s >= N_BI_) continue;
        const int kb = 2 * j + p;
        const float* xband = x + (size_t)(bb * N_BI_ + s) * D_IN_ * T_;
        for (int d_in = 0; d_in < D_IN_; ++d_in) {
            const float* xr = xband + d_in * T_;
            const float4 xc = *(const float4*)(xr + t0);
            float4 xp = make_float4(0.f, 0.f, 0.f, 0.f);
            if (t0 > 0) xp = *(const float4*)(xr + t0 - 4);
            const float xv[6] = {xp.z, xp.w, xc.x, xc.y, xc.z, xc.w};
#pragma unroll
            for (int kt = 0; kt < K_T_; ++kt) {
                float wv[8];
#pragma unroll
                for (int i = 0; i < 8; ++i) {
                    const int widx = __builtin_amdgcn_readfirstlane(
                        (((dog + i) * D_IN_ + d_in) * K_B_ + kb) * K_T_ + kt);
                    wv[i] = W[widx];
                }
#pragma unroll
                for (int i = 0; i < 8; ++i)
#pragma unroll
                    for (int u = 0; u < 4; ++u)
                        acc[i][u] = fmaf(wv[i], xv[u + kt], acc[i][u]);
            }
        }
    }
    if (act) {
        float bvv[8];
#pragma unroll
        for (int i = 0; i < 8; ++i) bvv[i] = bias[dog + i];
        float* op = out + ((size_t)(bb * N_BO_ + n) * D_OUT_ + dog) * T_ + t0;
#pragma unroll
        for (int i = 0; i < 8; ++i) {
            float4 v;
            v.x = acc[i][0] + bvv[i]; v.y = acc[i][1] + bvv[i];
            v.z = acc[i][2] + bvv[i]; v.w = acc[i][3] + bvv[i];
            *(float4*)(op + (size_t)i * T_) = v;
        }
    }
}

extern "C" void kernel_launch(void* const* d_in, const int* in_sizes, int n_in,
                              void* d_out, int out_size, void* d_ws, size_t ws_size,
                              hipStream_t stream) {
    const float* x    = (const float*)d_in[0];
    const float* W    = (const float*)d_in[1];
    const float* bias = (const float*)d_in[2];
    float* out = (float*)d_out;

    if (ws_size >= (size_t)WT_ELEMS * sizeof(__bf16)) {
        __bf16* wt = (__bf16*)d_ws;
        wprep<<<(WT_ELEMS + 255) / 256, 256, 0, stream>>>(W, wt);
        tct_pair<<<dim3(8 * 33 * 2), dim3(512), 0, stream>>>(x, wt, bias, out);
    } else {
        tct_fallback<<<dim3((T_ + 255) / 256, N_BO_, B_), dim3(256), 0, stream>>>(x, W, bias, out);
    }
}